// Round 1
// baseline (513.659 us; speedup 1.0000x reference)
//
#include <hip/hip_runtime.h>
#include <hip/hip_bf16.h>
#include <math.h>

// Problem constants
#define B_   32
#define T_   4096
#define CAT_ 128
#define NE_  512
#define HS_  64

// Pass-1 decomposition
#define CHUNKS_ 32              // blocks per batch row
#define ROWS_PER_BLOCK_ (T_ / CHUNKS_)   // 128
#define ROWS_PER_WAVE_  (ROWS_PER_BLOCK_ / 4) // 32 (4 waves / 256-thread block)

// ---------------------------------------------------------------------------
// K1: kq[b,n] = scale * sum_h Wk[n,h] * (sum_c cat_emb[b,c] * Wq[c,h])
// one wave per batch row; trivial cost
// ---------------------------------------------------------------------------
__global__ __launch_bounds__(64) void k_kq(const float* __restrict__ cat_emb,
                                           const float* __restrict__ Wq,
                                           const float* __restrict__ Wk,
                                           float* __restrict__ kq) {
    const int b = blockIdx.x;
    const int t = threadIdx.x;  // 0..63 == h
    __shared__ float sq[HS_];
    float q = 0.f;
    #pragma unroll 4
    for (int c = 0; c < CAT_; ++c) q += cat_emb[b * CAT_ + c] * Wq[c * HS_ + t];
    sq[t] = q;
    __syncthreads();
    #pragma unroll
    for (int i = 0; i < NE_ / 64; ++i) {
        const int n = i * 64 + t;
        float acc = 0.f;
        #pragma unroll 8
        for (int h = 0; h < HS_; ++h) acc += Wk[n * HS_ + h] * sq[h];
        kq[b * NE_ + n] = acc * 0.125f;  // scale = 1/sqrt(64)
    }
}

// ---------------------------------------------------------------------------
// K2: single streaming pass over x.
// For each row t: s = x[b,t,:]·kq[b,:]; online-softmax accumulate
//   acc[n] = sum_t exp(s_t - m) * x[b,t,n],  l = sum_t exp(s_t - m)
// One wave owns 32 consecutive rows; lane holds n in [4*lane,4*lane+4) and
// [256+4*lane, ...). Block combines its 4 waves in LDS -> one partial/block.
// ---------------------------------------------------------------------------
__global__ __launch_bounds__(256) void k_pass1(const float* __restrict__ x,
                                               const float* __restrict__ kq,
                                               float* __restrict__ pm,
                                               float* __restrict__ pl,
                                               float* __restrict__ pacc) {
    const int blk   = blockIdx.x;        // 0 .. B_*CHUNKS_-1
    const int b     = blk >> 5;          // CHUNKS_ = 32
    const int chunk = blk & 31;
    const int wave  = threadIdx.x >> 6;
    const int lane  = threadIdx.x & 63;

    const float4* kq4 = (const float4*)(kq + b * NE_);
    const float4 kq0 = kq4[lane];
    const float4 kq1 = kq4[lane + 64];

    const float* xb = x + (size_t)b * T_ * NE_;
    const int t0 = chunk * ROWS_PER_BLOCK_ + wave * ROWS_PER_WAVE_;

    float m = -INFINITY, l = 0.f;
    float a00 = 0.f, a01 = 0.f, a02 = 0.f, a03 = 0.f;
    float a10 = 0.f, a11 = 0.f, a12 = 0.f, a13 = 0.f;

    for (int r = 0; r < ROWS_PER_WAVE_; ++r) {
        const float4* xr = (const float4*)(xb + (size_t)(t0 + r) * NE_);
        const float4 x0 = xr[lane];
        const float4 x1 = xr[lane + 64];
        float p = x0.x * kq0.x + x0.y * kq0.y + x0.z * kq0.z + x0.w * kq0.w
                + x1.x * kq1.x + x1.y * kq1.y + x1.z * kq1.z + x1.w * kq1.w;
        #pragma unroll
        for (int off = 32; off >= 1; off >>= 1) p += __shfl_xor(p, off, 64);
        // p == full dot product, identical on all 64 lanes -> uniform branch-free update
        const float nm = fmaxf(m, p);
        const float f  = __expf(m - nm);   // 0 on first row (m = -inf)
        const float w  = __expf(p - nm);
        m = nm;
        l = l * f + w;
        a00 = a00 * f + w * x0.x;  a01 = a01 * f + w * x0.y;
        a02 = a02 * f + w * x0.z;  a03 = a03 * f + w * x0.w;
        a10 = a10 * f + w * x1.x;  a11 = a11 * f + w * x1.y;
        a12 = a12 * f + w * x1.z;  a13 = a13 * f + w * x1.w;
    }

    // block combine (4 waves -> 1 partial)
    __shared__ float sm[4], sl[4];
    __shared__ float sacc[4 * NE_];
    if (lane == 0) { sm[wave] = m; sl[wave] = l; }
    float4* sa = (float4*)(sacc + wave * NE_);
    sa[lane]      = make_float4(a00, a01, a02, a03);
    sa[lane + 64] = make_float4(a10, a11, a12, a13);
    __syncthreads();

    const float M  = fmaxf(fmaxf(sm[0], sm[1]), fmaxf(sm[2], sm[3]));
    const float f0 = __expf(sm[0] - M), f1 = __expf(sm[1] - M);
    const float f2 = __expf(sm[2] - M), f3 = __expf(sm[3] - M);
    const int n = threadIdx.x;  // 0..255; handles n and n+256
    float* dst = pacc + (size_t)blk * NE_;
    dst[n]       = f0 * sacc[0 * NE_ + n]       + f1 * sacc[1 * NE_ + n]
                 + f2 * sacc[2 * NE_ + n]       + f3 * sacc[3 * NE_ + n];
    dst[n + 256] = f0 * sacc[0 * NE_ + n + 256] + f1 * sacc[1 * NE_ + n + 256]
                 + f2 * sacc[2 * NE_ + n + 256] + f3 * sacc[3 * NE_ + n + 256];
    if (threadIdx.x == 0) {
        pm[blk] = M;
        pl[blk] = f0 * sl[0] + f1 * sl[1] + f2 * sl[2] + f3 * sl[3];
    }
}

// ---------------------------------------------------------------------------
// K3: per batch row: combine 32 partials -> xbar[512]; out = xbar @ Wv (512x64);
// y = out @ Wp (64x512); LayerNorm(y) -> ynorm[b,512]
// ---------------------------------------------------------------------------
__global__ __launch_bounds__(256) void k_combine(const float* __restrict__ pm,
                                                 const float* __restrict__ pl,
                                                 const float* __restrict__ pacc,
                                                 const float* __restrict__ Wv,
                                                 const float* __restrict__ Wp,
                                                 const float* __restrict__ gamma,
                                                 const float* __restrict__ beta,
                                                 float* __restrict__ ynorm) {
    const int b   = blockIdx.x;
    const int tid = threadIdx.x;  // 0..255
    __shared__ float xbar[NE_];
    __shared__ float sout[HS_];
    __shared__ float red[256];

    float M = -INFINITY;
    #pragma unroll
    for (int p = 0; p < CHUNKS_; ++p) M = fmaxf(M, pm[b * CHUNKS_ + p]);
    float L = 0.f, x0 = 0.f, x1 = 0.f;
    for (int p = 0; p < CHUNKS_; ++p) {
        const float f = __expf(pm[b * CHUNKS_ + p] - M);
        L += f * pl[b * CHUNKS_ + p];
        const float* a = pacc + (size_t)(b * CHUNKS_ + p) * NE_;
        x0 += f * a[tid];
        x1 += f * a[tid + 256];
    }
    const float rL = 1.f / L;
    xbar[tid] = x0 * rL;
    xbar[tid + 256] = x1 * rL;
    __syncthreads();

    // out[h] = sum_n xbar[n] * Wv[n,h] : 64 h-columns x 4 n-segments
    const int h = tid & 63, seg = tid >> 6;
    float o = 0.f;
    #pragma unroll 8
    for (int i = 0; i < NE_ / 4; ++i) {
        const int nn = seg * (NE_ / 4) + i;
        o += xbar[nn] * Wv[nn * HS_ + h];
    }
    red[tid] = o;
    __syncthreads();
    if (tid < 64) sout[tid] = red[tid] + red[tid + 64] + red[tid + 128] + red[tid + 192];
    __syncthreads();

    // y[nn] = sum_h sout[h] * Wp[h,nn]
    float y0 = 0.f, y1 = 0.f;
    #pragma unroll 8
    for (int hh = 0; hh < HS_; ++hh) {
        const float oh = sout[hh];
        y0 += oh * Wp[hh * NE_ + tid];
        y1 += oh * Wp[hh * NE_ + tid + 256];
    }

    // LayerNorm over 512
    red[tid] = y0 + y1;
    __syncthreads();
    for (int s = 128; s > 0; s >>= 1) { if (tid < s) red[tid] += red[tid + s]; __syncthreads(); }
    const float mu = red[0] * (1.f / NE_);
    __syncthreads();
    const float d0 = y0 - mu, d1 = y1 - mu;
    red[tid] = d0 * d0 + d1 * d1;
    __syncthreads();
    for (int s = 128; s > 0; s >>= 1) { if (tid < s) red[tid] += red[tid + s]; __syncthreads(); }
    const float rstd = rsqrtf(red[0] * (1.f / NE_) + 1e-5f);
    ynorm[b * NE_ + tid]       = d0 * rstd * gamma[tid]       + beta[tid];
    ynorm[b * NE_ + tid + 256] = d1 * rstd * gamma[tid + 256] + beta[tid + 256];
}

// ---------------------------------------------------------------------------
// K4: broadcast ynorm[b,:] over T -> out[b,t,:]. Pure coalesced float4 stores.
// Grid is exactly one b-slab (T*NE/4 = 524288 threads); each thread writes the
// same (t,n) position for b = 0..31 (ynorm read is L1/L2-resident).
// ---------------------------------------------------------------------------
__global__ __launch_bounds__(256) void k_bcast(const float4* __restrict__ y4,
                                               float4* __restrict__ out4) {
    const unsigned u = blockIdx.x * 256u + threadIdx.x;  // 0 .. 524287
    const int n4 = u & 127;  // position within the 512-float row (in float4s)
    #pragma unroll 4
    for (int b = 0; b < B_; ++b) {
        out4[(size_t)b * (T_ * NE_ / 4) + u] = y4[(b << 7) + n4];
    }
}

// ---------------------------------------------------------------------------
extern "C" void kernel_launch(void* const* d_in, const int* in_sizes, int n_in,
                              void* d_out, int out_size, void* d_ws, size_t ws_size,
                              hipStream_t stream) {
    const float* x       = (const float*)d_in[0];
    const float* cat_emb = (const float*)d_in[1];
    const float* Wq      = (const float*)d_in[2];
    const float* Wk      = (const float*)d_in[3];
    const float* Wv      = (const float*)d_in[4];
    const float* Wp      = (const float*)d_in[5];
    const float* gamma   = (const float*)d_in[6];
    const float* beta    = (const float*)d_in[7];
    float* out = (float*)d_out;

    // workspace layout (floats)
    float* ws    = (float*)d_ws;
    float* kq    = ws;                        // B*NE            = 16384
    float* pm    = kq + B_ * NE_;             // B*CHUNKS        = 1024
    float* pl    = pm + B_ * CHUNKS_;         // B*CHUNKS        = 1024
    float* pacc  = pl + B_ * CHUNKS_;         // B*CHUNKS*NE     = 524288
    float* ynorm = pacc + (size_t)B_ * CHUNKS_ * NE_;  // B*NE   = 16384

    k_kq<<<B_, 64, 0, stream>>>(cat_emb, Wq, Wk, kq);
    k_pass1<<<B_ * CHUNKS_, 256, 0, stream>>>(x, kq, pm, pl, pacc);
    k_combine<<<B_, 256, 0, stream>>>(pm, pl, pacc, Wv, Wp, gamma, beta, ynorm);
    k_bcast<<<(T_ * NE_ / 4) / 256, 256, 0, stream>>>((const float4*)ynorm, (float4*)out);
}

// Round 5
// 469.887 us; speedup vs baseline: 1.0932x; 1.0932x over previous
//
#include <hip/hip_runtime.h>
#include <hip/hip_bf16.h>
#include <math.h>

// Problem constants
#define B_   32
#define T_   4096
#define CAT_ 128
#define NE_  512
#define HS_  64

#define CHUNKS_ 32                      // blocks per batch row in K1
#define RPB_ (T_ / CHUNKS_)             // 128 rows per block
#define RPW_ (RPB_ / 4)                 // 32 rows per wave (4 waves/block)

typedef float f4 __attribute__((ext_vector_type(4)));  // clang-native vec for nontemporal builtins

// ---------------------------------------------------------------------------
// K1: fused. Phase A: every block computes kq[b] redundantly (L2-hot weights).
//     Phase B: stream own 128 rows of x once, online-softmax accumulate,
//     emit one partial (m, l, acc[512]) per block.
// ---------------------------------------------------------------------------
__global__ __launch_bounds__(256, 4) void k_main(
    const float* __restrict__ x, const float* __restrict__ cat_emb,
    const float* __restrict__ Wq, const float* __restrict__ Wk,
    float* __restrict__ pm, float* __restrict__ pl, float* __restrict__ pacc)
{
    const int blk   = blockIdx.x;        // 0..1023
    const int b     = blk >> 5;
    const int chunk = blk & 31;
    const int tid   = threadIdx.x;
    const int wave  = tid >> 6;
    const int lane  = tid & 63;

    __shared__ float sq[HS_];
    __shared__ float skq[NE_];
    __shared__ float red[256];
    __shared__ float sacc[4 * NE_];
    __shared__ float smw[4], slw[4];

    // ---- phase A: kq[n] = 0.125 * Wk[n,:] . (cat_emb[b,:] @ Wq)
    {
        const int h = tid & 63, cq = tid >> 6;
        float qp = 0.f;
        #pragma unroll 8
        for (int c = cq * 32; c < cq * 32 + 32; ++c)
            qp += cat_emb[b * CAT_ + c] * Wq[c * HS_ + h];
        red[tid] = qp;
        __syncthreads();
        if (tid < 64) sq[tid] = red[tid] + red[tid + 64] + red[tid + 128] + red[tid + 192];
        __syncthreads();
        const f4* Wk4 = (const f4*)Wk;
        const f4* sq4 = (const f4*)sq;
        #pragma unroll
        for (int half = 0; half < 2; ++half) {
            const int n = tid + half * 256;
            float acc = 0.f;
            #pragma unroll
            for (int i = 0; i < HS_ / 4; ++i) {
                const f4 w = Wk4[n * (HS_ / 4) + i];
                const f4 s = sq4[i];
                acc += w.x * s.x + w.y * s.y + w.z * s.z + w.w * s.w;
            }
            skq[n] = acc * 0.125f;       // scale = 1/sqrt(64)
        }
        __syncthreads();
    }

    // ---- phase B: stream + online softmax (identical math to round-1 pass)
    {
        const f4* kq4 = (const f4*)skq;
        const f4 kq0 = kq4[lane];
        const f4 kq1 = kq4[lane + 64];
        const float* xb = x + (size_t)b * T_ * NE_;
        const int t0 = chunk * RPB_ + wave * RPW_;

        float m = -INFINITY, l = 0.f;
        float a00 = 0.f, a01 = 0.f, a02 = 0.f, a03 = 0.f;
        float a10 = 0.f, a11 = 0.f, a12 = 0.f, a13 = 0.f;

        for (int r = 0; r < RPW_; ++r) {
            const f4* xr = (const f4*)(xb + (size_t)(t0 + r) * NE_);
            const f4 x0 = __builtin_nontemporal_load(&xr[lane]);
            const f4 x1 = __builtin_nontemporal_load(&xr[lane + 64]);
            float p = x0.x * kq0.x + x0.y * kq0.y + x0.z * kq0.z + x0.w * kq0.w
                    + x1.x * kq1.x + x1.y * kq1.y + x1.z * kq1.z + x1.w * kq1.w;
            #pragma unroll
            for (int off = 32; off >= 1; off >>= 1) p += __shfl_xor(p, off, 64);
            const float nm = fmaxf(m, p);
            const float f  = __expf(m - nm);   // 0 on first row (m = -inf)
            const float w  = __expf(p - nm);
            m = nm;
            l = l * f + w;
            a00 = a00 * f + w * x0.x;  a01 = a01 * f + w * x0.y;
            a02 = a02 * f + w * x0.z;  a03 = a03 * f + w * x0.w;
            a10 = a10 * f + w * x1.x;  a11 = a11 * f + w * x1.y;
            a12 = a12 * f + w * x1.z;  a13 = a13 * f + w * x1.w;
        }

        if (lane == 0) { smw[wave] = m; slw[wave] = l; }
        f4* sa = (f4*)(sacc + wave * NE_);
        f4 v0; v0.x = a00; v0.y = a01; v0.z = a02; v0.w = a03;
        f4 v1; v1.x = a10; v1.y = a11; v1.z = a12; v1.w = a13;
        sa[lane]      = v0;
        sa[lane + 64] = v1;
        __syncthreads();

        const float Mb = fmaxf(fmaxf(smw[0], smw[1]), fmaxf(smw[2], smw[3]));
        const float f0 = __expf(smw[0] - Mb), f1 = __expf(smw[1] - Mb);
        const float f2 = __expf(smw[2] - Mb), f3 = __expf(smw[3] - Mb);
        float* dst = pacc + (size_t)blk * NE_;
        dst[tid]       = f0 * sacc[tid]               + f1 * sacc[NE_ + tid]
                       + f2 * sacc[2 * NE_ + tid]     + f3 * sacc[3 * NE_ + tid];
        dst[tid + 256] = f0 * sacc[tid + 256]         + f1 * sacc[NE_ + tid + 256]
                       + f2 * sacc[2 * NE_ + tid + 256] + f3 * sacc[3 * NE_ + tid + 256];
        if (tid == 0) {
            pm[blk] = Mb;
            pl[blk] = f0 * slw[0] + f1 * slw[1] + f2 * slw[2] + f3 * slw[3];
        }
    }
}

// ---------------------------------------------------------------------------
// K2: per batch row: combine 32 partials -> xbar; xbar@Wv; @Wp; LayerNorm.
// ---------------------------------------------------------------------------
__global__ __launch_bounds__(256) void k_combine(const float* __restrict__ pm,
                                                 const float* __restrict__ pl,
                                                 const float* __restrict__ pacc,
                                                 const float* __restrict__ Wv,
                                                 const float* __restrict__ Wp,
                                                 const float* __restrict__ gamma,
                                                 const float* __restrict__ beta,
                                                 float* __restrict__ ynorm) {
    const int b   = blockIdx.x;
    const int tid = threadIdx.x;
    __shared__ float xbar[NE_];
    __shared__ float sout[HS_];
    __shared__ float red[256];

    float M = -INFINITY;
    #pragma unroll
    for (int p = 0; p < CHUNKS_; ++p) M = fmaxf(M, pm[b * CHUNKS_ + p]);
    float L = 0.f, x0 = 0.f, x1 = 0.f;
    for (int p = 0; p < CHUNKS_; ++p) {
        const float f = __expf(pm[b * CHUNKS_ + p] - M);
        L += f * pl[b * CHUNKS_ + p];
        const float* a = pacc + (size_t)(b * CHUNKS_ + p) * NE_;
        x0 += f * a[tid];
        x1 += f * a[tid + 256];
    }
    const float rL = 1.f / L;
    xbar[tid] = x0 * rL;
    xbar[tid + 256] = x1 * rL;
    __syncthreads();

    const int h = tid & 63, seg = tid >> 6;
    float o = 0.f;
    #pragma unroll 8
    for (int i = 0; i < NE_ / 4; ++i) {
        const int nn = seg * (NE_ / 4) + i;
        o += xbar[nn] * Wv[nn * HS_ + h];
    }
    red[tid] = o;
    __syncthreads();
    if (tid < 64) sout[tid] = red[tid] + red[tid + 64] + red[tid + 128] + red[tid + 192];
    __syncthreads();

    float y0 = 0.f, y1 = 0.f;
    #pragma unroll 8
    for (int hh = 0; hh < HS_; ++hh) {
        const float oh = sout[hh];
        y0 += oh * Wp[hh * NE_ + tid];
        y1 += oh * Wp[hh * NE_ + tid + 256];
    }

    red[tid] = y0 + y1;
    __syncthreads();
    for (int s = 128; s > 0; s >>= 1) { if (tid < s) red[tid] += red[tid + s]; __syncthreads(); }
    const float mu = red[0] * (1.f / NE_);
    __syncthreads();
    const float d0 = y0 - mu, d1 = y1 - mu;
    red[tid] = d0 * d0 + d1 * d1;
    __syncthreads();
    for (int s = 128; s > 0; s >>= 1) { if (tid < s) red[tid] += red[tid + s]; __syncthreads(); }
    const float rstd = rsqrtf(red[0] * (1.f / NE_) + 1e-5f);
    ynorm[b * NE_ + tid]       = d0 * rstd * gamma[tid]       + beta[tid];
    ynorm[b * NE_ + tid + 256] = d1 * rstd * gamma[tid + 256] + beta[tid + 256];
}

// ---------------------------------------------------------------------------
// K3: broadcast. Each block writes one CONTIGUOUS 128 KB span (one b, 64 rows).
// Per-thread yn value is loop-invariant; stores walk sequentially, nontemporal.
// ---------------------------------------------------------------------------
__global__ __launch_bounds__(256) void k_bcast(const f4* __restrict__ yn4,
                                               f4* __restrict__ out4) {
    const int blk = blockIdx.x;          // 0..2047
    const int b   = blk >> 6;            // 64 blocks per batch row
    const int seg = blk & 63;            // 64 rows each
    const int tid = threadIdx.x;
    const f4 v = yn4[(b << 7) + (tid & 127)];   // (tid + i*256) & 127 == tid & 127
    const size_t base = ((size_t)b * T_ + (size_t)seg * 64) * (NE_ / 4);
    f4* p = out4 + base + tid;
    #pragma unroll 8
    for (int i = 0; i < 32; ++i) {
        __builtin_nontemporal_store(v, p + (size_t)i * 256);
    }
}

// ---------------------------------------------------------------------------
extern "C" void kernel_launch(void* const* d_in, const int* in_sizes, int n_in,
                              void* d_out, int out_size, void* d_ws, size_t ws_size,
                              hipStream_t stream) {
    const float* x       = (const float*)d_in[0];
    const float* cat_emb = (const float*)d_in[1];
    const float* Wq      = (const float*)d_in[2];
    const float* Wk      = (const float*)d_in[3];
    const float* Wv      = (const float*)d_in[4];
    const float* Wp      = (const float*)d_in[5];
    const float* gamma   = (const float*)d_in[6];
    const float* beta    = (const float*)d_in[7];
    float* out = (float*)d_out;

    float* ws    = (float*)d_ws;
    float* pm    = ws;                                 // 1024
    float* pl    = pm + B_ * CHUNKS_;                  // 1024
    float* pacc  = pl + B_ * CHUNKS_;                  // 1024*512
    float* ynorm = pacc + (size_t)B_ * CHUNKS_ * NE_;  // 32*512

    k_main<<<B_ * CHUNKS_, 256, 0, stream>>>(x, cat_emb, Wq, Wk, pm, pl, pacc);
    k_combine<<<B_, 256, 0, stream>>>(pm, pl, pacc, Wv, Wp, gamma, beta, ynorm);
    k_bcast<<<2048, 256, 0, stream>>>((const f4*)ynorm, (f4*)out);
}